// Round 3
// baseline (299.161 us; speedup 1.0000x reference)
//
#include <hip/hip_runtime.h>
#include <cstdint>

// Problem constants (match reference)
#define TOK 2048
#define HD  1024
#define ID  768
#define NE  32
#define RT  2     // row-tile grid depth (stride loop handles overflow)

typedef unsigned short u16t;
typedef unsigned int   u32t;
typedef __bf16 bf16x8 __attribute__((ext_vector_type(8)));
typedef float  f32x4  __attribute__((ext_vector_type(4)));
typedef u16t   u16x8  __attribute__((ext_vector_type(8)));
typedef u16t   u16x4  __attribute__((ext_vector_type(4)));
typedef float  fvec4  __attribute__((ext_vector_type(4)));

// f32 -> bf16 round-to-nearest-even
__device__ __forceinline__ u16t f2b(float f) {
  u32t u = __float_as_uint(f);
  u32t r = u + 0x7fffu + ((u >> 16) & 1u);
  return (u16t)(r >> 16);
}

// LDS granule swizzle: granule = 8 bf16 (16B). Layout [row][4 granules of k].
// XOR k-chunk with (row>>2)&3; same helper for write and read.
__device__ __forceinline__ int swz(int row, int kc) {
  return (row * 4 + (kc ^ ((row >> 2) & 3))) * 8;   // index in u16 units
}

// ---------------------------------------------------------------- k_cvt ----
__global__ void k_cvt(const float* __restrict__ x, u16t* __restrict__ xb) {
  int i = (blockIdx.x * 256 + threadIdx.x) * 4;
  fvec4 v = *(const fvec4*)(x + i);
  u16x4 o = { f2b(v[0]), f2b(v[1]), f2b(v[2]), f2b(v[3]) };
  *(u16x4*)(xb + i) = o;
}

// -------------------------------------------------------------- k_router ---
__global__ void k_router(const float* __restrict__ x, const float* __restrict__ gw,
                         const float* __restrict__ eb,
                         int* __restrict__ topk_ids, float* __restrict__ topk_w,
                         int* __restrict__ counts) {
  int lane = threadIdx.x & 63;
  int t = blockIdx.x * 4 + (threadIdx.x >> 6);
  const float* xt = x + (size_t)t * HD;
  fvec4 xr[4];
#pragma unroll
  for (int i = 0; i < 4; ++i) xr[i] = *(const fvec4*)(xt + lane * 4 + i * 256);
  float myscore = 0.f;
  for (int e = 0; e < NE; ++e) {
    const float* ge = gw + (size_t)e * HD + lane * 4;
    float s = 0.f;
#pragma unroll
    for (int i = 0; i < 4; ++i) {
      fvec4 g = *(const fvec4*)(ge + i * 256);
      s = fmaf(xr[i][0], g[0], s); s = fmaf(xr[i][1], g[1], s);
      s = fmaf(xr[i][2], g[2], s); s = fmaf(xr[i][3], g[3], s);
    }
#pragma unroll
    for (int off = 32; off; off >>= 1) s += __shfl_xor(s, off);
    if (lane == e) myscore = s;
  }
  float sig = 1.f / (1.f + expf(-myscore));
  float biased = (lane < NE) ? (sig + eb[lane]) : -3.0e38f;
  float wsum = 0.f;
  int ids[4]; float wsv[4];
#pragma unroll
  for (int k = 0; k < 4; ++k) {
    float v = biased; int idx = lane;
#pragma unroll
    for (int off = 32; off; off >>= 1) {
      float ov = __shfl_xor(v, off);
      int   oi = __shfl_xor(idx, off);
      if (ov > v || (ov == v && oi < idx)) { v = ov; idx = oi; }
    }
    ids[k] = idx;
    float sc = __shfl(sig, idx);   // uncorrected sigmoid score is the weight
    wsv[k] = sc; wsum += sc;
    if (lane == idx) biased = -3.0e38f;
  }
  float inv = 1.f / wsum;
#pragma unroll
  for (int k = 0; k < 4; ++k) {
    if (lane == k) {
      topk_ids[t * 4 + k] = ids[k];
      topk_w[t * 4 + k]  = wsv[k] * inv;
      atomicAdd(&counts[ids[k]], 1);
    }
  }
}

// -------------------------------------------------------------- k_bucket ---
__global__ void k_bucket(const int* __restrict__ topk_ids, const float* __restrict__ topk_w,
                         const int* __restrict__ counts, int* __restrict__ offsets,
                         int* __restrict__ pairTok, float* __restrict__ pairW,
                         int* __restrict__ invp) {
  __shared__ int soff[NE + 1];
  __shared__ int scur[NE];
  int tid = threadIdx.x;
  if (tid == 0) {
    int acc = 0;
    for (int e = 0; e < NE; ++e) { soff[e] = acc; acc += counts[e]; }
    soff[NE] = acc;
  }
  if (tid < NE) scur[tid] = 0;
  __syncthreads();
  if (tid <= NE) offsets[tid] = soff[tid];
  for (int p = tid; p < TOK * 4; p += 256) {
    int e = topk_ids[p];
    int pos = soff[e] + atomicAdd(&scur[e], 1);
    pairTok[pos] = p;          // p = t*4+k
    pairW[pos]   = topk_w[p];
    invp[p]      = pos;
  }
}

// --------------------------------------------------------------- k_gemm1 ---
// grid (24 col-tiles of 32, 32 experts, RT). Block 256 thr / 4 row-waves.
// Tile 256 rows x 32 cols x {w1,w3}. A-frags direct from global (no X LDS).
// W: LDS ping-pong, 2-step register prefetch, ONE barrier per K-step.
#define G1_WLOAD(d0, d1, KK) do { \
    const float* _s = wp + (size_t)((KK) + hg * 2) * ID + wcol; \
    d0 = *(const fvec4*)(_s); d1 = *(const fvec4*)(_s + ID); } while (0)

#define G1_WSTORE(BUF, d0, d1) do { \
    _Pragma("unroll") for (int c = 0; c < 4; ++c) { \
      u32t pk = (u32t)f2b(d0[c]) | ((u32t)f2b(d1[c]) << 16); \
      *(u32t*)&Ws[BUF][mat][swz(cg4 + c, kcw) + offw] = pk; } } while (0)

#define G1_AFLOAD(AF, KK) do { \
    _Pragma("unroll") for (int rf = 0; rf < 4; ++rf) \
      AF[rf] = *(const u16x8*)(xb + (size_t)tok[rf] * HD + (KK) + klo); } while (0)

#define G1_MFMA(AF, BUF) do { \
    bf16x8 b0 = *(const bf16x8*)&Ws[BUF][0][swz(col0, kcl)]; \
    bf16x8 b1 = *(const bf16x8*)&Ws[BUF][0][swz(col1, kcl)]; \
    bf16x8 b2 = *(const bf16x8*)&Ws[BUF][1][swz(col0, kcl)]; \
    bf16x8 b3 = *(const bf16x8*)&Ws[BUF][1][swz(col1, kcl)]; \
    _Pragma("unroll") for (int rf = 0; rf < 4; ++rf) { \
      acc[rf][0][0] = __builtin_amdgcn_mfma_f32_16x16x32_bf16(AF[rf], b0, acc[rf][0][0], 0, 0, 0); \
      acc[rf][1][0] = __builtin_amdgcn_mfma_f32_16x16x32_bf16(AF[rf], b1, acc[rf][1][0], 0, 0, 0); \
      acc[rf][0][1] = __builtin_amdgcn_mfma_f32_16x16x32_bf16(AF[rf], b2, acc[rf][0][1], 0, 0, 0); \
      acc[rf][1][1] = __builtin_amdgcn_mfma_f32_16x16x32_bf16(AF[rf], b3, acc[rf][1][1], 0, 0, 0); } } while (0)

__launch_bounds__(256, 3)
__global__ void k_gemm1(const u16t* __restrict__ xb, const float* __restrict__ w1,
                        const float* __restrict__ w3,
                        const int* __restrict__ counts, const int* __restrict__ offsets,
                        const int* __restrict__ pairTok, const float* __restrict__ pairW,
                        u16t* __restrict__ A) {
  const int e = blockIdx.y;
  const int colbase = blockIdx.x * 32;
  const int count = counts[e];
  const int base  = offsets[e];
  const int tid = threadIdx.x, lane = tid & 63, wv = tid >> 6;

  __shared__ __align__(16) u16t Ws[2][2][1024];  // [buf][mat][32c x 32k] 8 KB
  __shared__ float pw[256];

  const int mat = tid >> 7;
  const float* wp = (mat ? w3 : w1) + (size_t)e * HD * ID;
  const int u = tid & 127;
  const int cg4 = (u & 7) * 4, hg = u >> 3;          // 4 cols, 2 k-rows/thread
  const int kcw = hg >> 2, offw = (hg & 3) * 2;
  const int wcol = colbase + cg4;
  const int klo = (lane >> 4) * 8;
  const int col0 = lane & 15, col1 = col0 + 16, kcl = lane >> 4;

  for (int r0 = blockIdx.z * 256; r0 < count; r0 += RT * 256) {
    __syncthreads();    // prev iteration's pw readers / LDS readers done
    {
      int idx = r0 + tid;
      pw[tid] = (idx < count) ? pairW[base + idx] : 0.f;
    }
    int tok[4];
#pragma unroll
    for (int rf = 0; rf < 4; ++rf) {
      int idx = r0 + wv * 64 + rf * 16 + (lane & 15);
      idx = idx < count ? idx : count - 1;
      tok[rf] = pairTok[base + idx] >> 2;
    }

    f32x4 zz = {0.f, 0.f, 0.f, 0.f};
    f32x4 acc[4][2][2];
#pragma unroll
    for (int a = 0; a < 4; ++a)
#pragma unroll
      for (int b = 0; b < 2; ++b) { acc[a][b][0] = zz; acc[a][b][1] = zz; }

    fvec4 wdA0, wdA1, wdB0, wdB1;
    u16x8 afC[4], afD[4];
    // prologue: LDS[0]=W0; wdB=W1; wdA=W2; afC=af(0)
    G1_WLOAD(wdA0, wdA1, 0);
    G1_WLOAD(wdB0, wdB1, 32);
    G1_AFLOAD(afC, 0);
    G1_WSTORE(0, wdA0, wdA1);
    G1_WLOAD(wdA0, wdA1, 64);

    for (int s = 0; s < 32; s += 2) {
      const int kk = s * 32;
      // even step: read LDS[0] (W s), write LDS[1]=W(s+1), issue W(s+3), af(s+1)
      __syncthreads();
      G1_WSTORE(1, wdB0, wdB1);
      if (s + 3 < 32) G1_WLOAD(wdB0, wdB1, kk + 96);
      G1_AFLOAD(afD, kk + 32);
      G1_MFMA(afC, 0);
      // odd step: read LDS[1], write LDS[0]=W(s+2), issue W(s+4), af(s+2)
      __syncthreads();
      if (s + 2 < 32) G1_WSTORE(0, wdA0, wdA1);
      if (s + 4 < 32) G1_WLOAD(wdA0, wdA1, kk + 128);
      if (s + 2 < 32) G1_AFLOAD(afC, kk + 64);
      G1_MFMA(afD, 1);
    }
    // epilogue: a = silu(g)*u*routing_w -> A (bf16)
#pragma unroll
    for (int rf = 0; rf < 4; ++rf)
#pragma unroll
      for (int ri = 0; ri < 4; ++ri) {
        int rowl = wv * 64 + rf * 16 + (lane >> 4) * 4 + ri;
        int grow = r0 + rowl;
        if (grow < count) {
          float wgt = pw[rowl];
#pragma unroll
          for (int cf = 0; cf < 2; ++cf) {
            float gg = acc[rf][cf][0][ri];
            float uu = acc[rf][cf][1][ri];
            float a = gg / (1.f + expf(-gg)) * uu * wgt;
            A[(size_t)(base + grow) * ID + colbase + cf * 16 + (lane & 15)] = f2b(a);
          }
        }
      }
  }
}

// --------------------------------------------------------------- k_gemm2 ---
// grid (32 col-tiles of 32, 32 experts, RT). Tile 256 x 32, acc 32 AGPR.
#define G2_WLOAD(d, KK) \
    d = *(const fvec4*)(w2e + (size_t)((KK) + kg) * HD + wcol)

#define G2_WSTORE(BUF, d) do { \
    _Pragma("unroll") for (int c = 0; c < 4; ++c) \
      W2s[BUF][swz(cg4 + c, kcw) + offw] = f2b(d[c]); } while (0)

#define G2_AFLOAD(AF, KK) do { \
    _Pragma("unroll") for (int rf = 0; rf < 4; ++rf) \
      AF[rf] = *(const u16x8*)(Ab + (size_t)arow[rf] * ID + (KK) + klo); } while (0)

#define G2_MFMA(AF, BUF) do { \
    bf16x8 b0 = *(const bf16x8*)&W2s[BUF][swz(col0, kcl)]; \
    bf16x8 b1 = *(const bf16x8*)&W2s[BUF][swz(col1, kcl)]; \
    _Pragma("unroll") for (int rf = 0; rf < 4; ++rf) { \
      acc[rf][0] = __builtin_amdgcn_mfma_f32_16x16x32_bf16(AF[rf], b0, acc[rf][0], 0, 0, 0); \
      acc[rf][1] = __builtin_amdgcn_mfma_f32_16x16x32_bf16(AF[rf], b1, acc[rf][1], 0, 0, 0); } } while (0)

__launch_bounds__(256, 4)
__global__ void k_gemm2(const u16t* __restrict__ Ab, const float* __restrict__ w2,
                        const int* __restrict__ counts, const int* __restrict__ offsets,
                        float* __restrict__ buf) {
  const int e = blockIdx.y;
  const int colbase = blockIdx.x * 32;
  const int count = counts[e];
  const int base  = offsets[e];
  const int tid = threadIdx.x, lane = tid & 63, wv = tid >> 6;

  __shared__ __align__(16) u16t W2s[2][1024];   // [buf][32c x 32k] 4 KB

  const float* w2e = w2 + (size_t)e * ID * HD;
  const int cg4 = (tid & 7) * 4, kg = tid >> 3;  // 4 cols, 1 k-row/thread
  const int kcw = kg >> 3, offw = kg & 7;
  const int wcol = colbase + cg4;
  const int klo = (lane >> 4) * 8;
  const int col0 = lane & 15, col1 = col0 + 16, kcl = lane >> 4;

  for (int r0 = blockIdx.z * 256; r0 < count; r0 += RT * 256) {
    int arow[4];
#pragma unroll
    for (int rf = 0; rf < 4; ++rf) {
      int idx = r0 + wv * 64 + rf * 16 + (lane & 15);
      idx = idx < count ? idx : count - 1;
      arow[rf] = base + idx;
    }
    f32x4 zz = {0.f, 0.f, 0.f, 0.f};
    f32x4 acc[4][2];
#pragma unroll
    for (int a = 0; a < 4; ++a) { acc[a][0] = zz; acc[a][1] = zz; }

    fvec4 wdA, wdB;
    u16x8 afC[4], afD[4];
    G2_WLOAD(wdA, 0);
    G2_WLOAD(wdB, 32);
    G2_AFLOAD(afC, 0);
    G2_WSTORE(0, wdA);
    G2_WLOAD(wdA, 64);

    for (int s = 0; s < 24; s += 2) {
      const int kk = s * 32;
      __syncthreads();
      G2_WSTORE(1, wdB);
      if (s + 3 < 24) G2_WLOAD(wdB, kk + 96);
      G2_AFLOAD(afD, kk + 32);
      G2_MFMA(afC, 0);
      __syncthreads();
      if (s + 2 < 24) G2_WSTORE(0, wdA);
      if (s + 4 < 24) G2_WLOAD(wdA, kk + 128);
      if (s + 2 < 24) G2_AFLOAD(afC, kk + 64);
      G2_MFMA(afD, 1);
    }
#pragma unroll
    for (int rf = 0; rf < 4; ++rf)
#pragma unroll
      for (int ri = 0; ri < 4; ++ri) {
        int rowl = wv * 64 + rf * 16 + (lane >> 4) * 4 + ri;
        int grow = r0 + rowl;
        if (grow < count) {
#pragma unroll
          for (int cf = 0; cf < 2; ++cf)
            buf[(size_t)(base + grow) * HD + colbase + cf * 16 + (lane & 15)] = acc[rf][cf][ri];
        }
      }
    __syncthreads();   // LDS reuse safety across r0 iterations
  }
}

// -------------------------------------------------------------- k_reduce ---
__global__ void k_reduce(const float* __restrict__ buf, const int* __restrict__ invp,
                         float* __restrict__ out) {
  int t = blockIdx.x;
  int col = threadIdx.x * 4;
  int p0 = invp[t * 4 + 0], p1 = invp[t * 4 + 1];
  int p2 = invp[t * 4 + 2], p3 = invp[t * 4 + 3];
  fvec4 s = *(const fvec4*)(buf + (size_t)p0 * HD + col);
  s += *(const fvec4*)(buf + (size_t)p1 * HD + col);
  s += *(const fvec4*)(buf + (size_t)p2 * HD + col);
  s += *(const fvec4*)(buf + (size_t)p3 * HD + col);
  *(fvec4*)(out + (size_t)t * HD + col) = s;
}

// ------------------------------------------------------------------ host ---
extern "C" void kernel_launch(void* const* d_in, const int* in_sizes, int n_in,
                              void* d_out, int out_size, void* d_ws, size_t ws_size,
                              hipStream_t stream) {
  const float* x  = (const float*)d_in[0];
  const float* gw = (const float*)d_in[1];
  const float* w1 = (const float*)d_in[2];
  const float* w3 = (const float*)d_in[3];
  const float* w2 = (const float*)d_in[4];
  const float* eb = (const float*)d_in[5];
  float* out = (float*)d_out;

  char* ws = (char*)d_ws;
  int*   counts   = (int*)(ws);               // [32]   (zeroed)
  int*   offsets  = (int*)(ws + 256);         // [33]
  int*   topk_ids = (int*)(ws + 4096);        // [8192]
  float* topk_w   = (float*)(ws + 36864);     // [8192]
  int*   pairTok  = (int*)(ws + 69632);       // [8192]
  float* pairW    = (float*)(ws + 102400);    // [8192]
  int*   invp     = (int*)(ws + 135168);      // [8192]
  u16t*  xb       = (u16t*)(ws + 262144);                 // [2048*1024] bf16
  u16t*  Abuf     = (u16t*)(ws + 262144 + 4194304);       // [8192*768]  bf16
  float* buf      = (float*)(ws + 262144 + 4194304 + 12582912); // [8192*1024] f32

  hipMemsetAsync(counts, 0, 4096, stream);
  k_cvt   <<<2048, 256, 0, stream>>>(x, xb);
  k_router<<<512, 256, 0, stream>>>(x, gw, eb, topk_ids, topk_w, counts);
  k_bucket<<<1, 256, 0, stream>>>(topk_ids, topk_w, counts, offsets, pairTok, pairW, invp);
  k_gemm1 <<<dim3(24, 32, RT), 256, 0, stream>>>(xb, w1, w3, counts, offsets, pairTok, pairW, Abuf);
  k_gemm2 <<<dim3(32, 32, RT), 256, 0, stream>>>(Abuf, w2, counts, offsets, buf);
  k_reduce<<<2048, 256, 0, stream>>>(buf, invp, out);
}